// Round 3
// baseline (2076.244 us; speedup 1.0000x reference)
//
#include <hip/hip_runtime.h>
#include <hip/hip_bf16.h>
#include <hip/hip_cooperative_groups.h>

namespace cg = cooperative_groups;

#define L_ 8
#define M_ 128
#define K_ 32
#define D_ 16
#define B_ 2048
#define N_ 1024           // L_*M_
#define SLAB_ 32768       // B_*D_ elements per node slab
#define NBLK 1024

// ===========================================================================
// Fused persistent cooperative kernel: transpose + all 8 layers.
// grid = 1024 blocks x 256 threads, 4 blocks/CU co-resident.
// ===========================================================================
__global__ __launch_bounds__(256, 4) void fused_all(
    const float* __restrict__ x, const float* __restrict__ trace,
    const int* __restrict__ sn, const int* __restrict__ sf,
    const float* __restrict__ W, const float* __restrict__ bias,
    float* __restrict__ out, float* __restrict__ xT,
    float* __restrict__ traceT, float* __restrict__ outT)
{
    cg::grid_group grid = cg::this_grid();
    const int blk = blockIdx.x;
    const int tid = threadIdx.x;

    // big: transpose tile (16 x 257 = 4112 floats) OR osh (256 x 17 = 4352).
    __shared__ float        big[4352];
    __shared__ float        Wsh[D_ * K_];
    __shared__ float        bsh[D_];
    __shared__ const float* colp[K_];

    // ---- Phase 0: transpose (B_,D_) slabs -> (D_,B_). Tile = 256b x 16d. ----
    // trace: 1024 slabs x 8 tiles; x: 8 tiles. 8200 tiles over 1024 blocks.
    for (int t = blk; t < N_ * 8 + 8; t += NBLK) {
        const float* src; float* dst; int bt;
        if (t < N_ * 8) {
            int nn = t >> 3;
            src = trace + (size_t)nn * SLAB_;
            dst = traceT + (size_t)nn * SLAB_;
            bt  = t & 7;
        } else {
            src = x; dst = xT; bt = t - N_ * 8;
        }
        int b0 = bt * 256;

        // Load 256 b-rows x 16 d = 16 KB contiguous; 4 float4/thread in flight.
        const float4* s4 = (const float4*)(src + (size_t)b0 * D_);
        float4 v0 = s4[tid * 4 + 0];
        float4 v1 = s4[tid * 4 + 1];
        float4 v2 = s4[tid * 4 + 2];
        float4 v3 = s4[tid * 4 + 3];
        __syncthreads();     // previous iteration's readers are done
        // row stride 257: write banks distinct per lane; read <=2-way. Free.
        big[(0 * 4 + 0) * 257 + tid] = v0.x;  big[(0 * 4 + 1) * 257 + tid] = v0.y;
        big[(0 * 4 + 2) * 257 + tid] = v0.z;  big[(0 * 4 + 3) * 257 + tid] = v0.w;
        big[(1 * 4 + 0) * 257 + tid] = v1.x;  big[(1 * 4 + 1) * 257 + tid] = v1.y;
        big[(1 * 4 + 2) * 257 + tid] = v1.z;  big[(1 * 4 + 3) * 257 + tid] = v1.w;
        big[(2 * 4 + 0) * 257 + tid] = v2.x;  big[(2 * 4 + 1) * 257 + tid] = v2.y;
        big[(2 * 4 + 2) * 257 + tid] = v2.z;  big[(2 * 4 + 3) * 257 + tid] = v2.w;
        big[(3 * 4 + 0) * 257 + tid] = v3.x;  big[(3 * 4 + 1) * 257 + tid] = v3.y;
        big[(3 * 4 + 2) * 257 + tid] = v3.z;  big[(3 * 4 + 3) * 257 + tid] = v3.w;
        __syncthreads();

        // Store 16 d-rows of 256 b (1 KB contiguous per row-chunk), 4 f4/thread.
        int d  = tid >> 4;
        int q0 = tid & 15;
        float* drow = dst + (size_t)d * B_ + b0;
#pragma unroll
        for (int j = 0; j < 4; ++j) {
            int bq = q0 + 16 * j;
            float4 w;
            w.x = big[d * 257 + 4 * bq + 0];
            w.y = big[d * 257 + 4 * bq + 1];
            w.z = big[d * 257 + 4 * bq + 2];
            w.w = big[d * 257 + 4 * bq + 3];
            ((float4*)drow)[bq] = w;
        }
    }

    __threadfence();         // device-scope release of traceT/xT (cross-XCD)
    grid.sync();

    // ---- Phases 1..8: layers. Block (m,bt) identity is fixed across layers. ----
    const int m  = blk >> 3;
    const int bt = blk & 7;
    const int b  = bt * 256 + tid;

    for (int l = 0; l < L_; ++l) {
        const int n = l * M_ + m;

        if (tid < 128) {
            ((float4*)Wsh)[tid] = ((const float4*)(W + (size_t)n * D_ * K_))[tid];
        }
        if (tid < D_) bsh[tid] = bias[(size_t)n * D_ + tid];
        if (tid < K_) {
            int s = sn[(size_t)n * K_ + tid];
            int f = sf[(size_t)n * K_ + tid];
            const float* p;
            if (s == 0) {
                p = xT + (size_t)f * B_;
            } else {
                int ls = (s - 1) >> 7;
                if (ls >= l) p = traceT + (size_t)(s - 1) * SLAB_ + (size_t)f * B_;
                else         p = outT   + (size_t)(s - 1) * SLAB_ + (size_t)f * B_;
            }
            colp[tid] = p;
        }
        __syncthreads();

        // Gather: 32 coalesced 256 B wave-loads.
        float g[K_];
#pragma unroll
        for (int k = 0; k < K_; ++k) g[k] = colp[k][b];

        // o[d] = relu(bias + g . W[d,:]); write outT (unit-stride), stage osh.
#pragma unroll
        for (int d = 0; d < D_; ++d) {
            float acc = bsh[d];
#pragma unroll
            for (int k = 0; k < K_; ++k) acc = fmaf(g[k], Wsh[d * K_ + k], acc);
            acc = fmaxf(acc, 0.0f);
            big[tid * 17 + d] = acc;
            outT[(size_t)n * SLAB_ + (size_t)d * B_ + b] = acc;
        }
        __syncthreads();

        // Native out: block region out[n, bt*256 .., :] = 16 KB contiguous.
        float4* region4 = (float4*)(out + (size_t)n * SLAB_ + (size_t)(bt * 256) * D_);
#pragma unroll
        for (int j = 0; j < 4; ++j) {
            int i   = j * 256 + tid;
            int row = i >> 2;
            int c0  = (i & 3) * 4;
            float4 w;
            w.x = big[row * 17 + c0 + 0];
            w.y = big[row * 17 + c0 + 1];
            w.z = big[row * 17 + c0 + 2];
            w.w = big[row * 17 + c0 + 3];
            region4[i] = w;
        }

        if (l < L_ - 1) {
            __threadfence();  // outT visible across XCDs before next layer
            grid.sync();
        }
    }
}

// ===========================================================================
// Fallback multi-dispatch path (R1 structure), used if cooperative launch
// is unavailable.
// ===========================================================================
__global__ __launch_bounds__(256) void transpose_bd(const float* __restrict__ trace,
                                                    const float* __restrict__ x,
                                                    float* __restrict__ traceT,
                                                    float* __restrict__ xT) {
    int blk = blockIdx.x;
    const float* src; float* dst; int bt;
    if (blk < N_ * 32) {
        int n = blk >> 5;
        src = trace + (size_t)n * SLAB_;
        dst = traceT + (size_t)n * SLAB_;
        bt  = blk & 31;
    } else {
        src = x; dst = xT; bt = blk - N_ * 32;
    }
    int b0 = bt * 64;
    __shared__ float lds[D_][65];
    int tid = threadIdx.x;
    const float4* s4 = (const float4*)src;
    int b  = tid >> 2;
    int dq = tid & 3;
    float4 v = s4[(size_t)(b0 + b) * 4 + dq];
    lds[dq * 4 + 0][b] = v.x;
    lds[dq * 4 + 1][b] = v.y;
    lds[dq * 4 + 2][b] = v.z;
    lds[dq * 4 + 3][b] = v.w;
    __syncthreads();
    int d  = tid >> 4;
    int bq = tid & 15;
    float4 w;
    w.x = lds[d][bq * 4 + 0];
    w.y = lds[d][bq * 4 + 1];
    w.z = lds[d][bq * 4 + 2];
    w.w = lds[d][bq * 4 + 3];
    ((float4*)(dst + (size_t)d * B_ + b0))[bq] = w;
}

__global__ __launch_bounds__(256) void layer_kernel(
    int l,
    const float* __restrict__ xbuf,
    const float* __restrict__ tbuf,
    const float* __restrict__ obuf,
    const int* __restrict__ sn, const int* __restrict__ sf,
    const float* __restrict__ W, const float* __restrict__ bias,
    float* __restrict__ out, float* __restrict__ outT)
{
    int m  = blockIdx.x >> 3;
    int bt = blockIdx.x & 7;
    int n  = l * M_ + m;
    int b  = bt * 256 + threadIdx.x;

    __shared__ float        Wsh[D_][K_];
    __shared__ float        bsh[D_];
    __shared__ const float* colp[K_];
    __shared__ float        osh[256][17];

    int tid = threadIdx.x;
    if (tid < 128) {
        ((float4*)&Wsh[0][0])[tid] = ((const float4*)(W + (size_t)n * D_ * K_))[tid];
    }
    if (tid < D_) bsh[tid] = bias[(size_t)n * D_ + tid];
    if (tid < K_) {
        int s = sn[(size_t)n * K_ + tid];
        int f = sf[(size_t)n * K_ + tid];
        const float* p;
        if (s == 0) p = xbuf + (size_t)f * B_;
        else {
            int ls = (s - 1) >> 7;
            if (ls >= l) p = tbuf + (size_t)(s - 1) * SLAB_ + (size_t)f * B_;
            else         p = obuf + (size_t)(s - 1) * SLAB_ + (size_t)f * B_;
        }
        colp[tid] = p;
    }
    __syncthreads();

    float g[K_];
#pragma unroll
    for (int k = 0; k < K_; ++k) g[k] = colp[k][b];

#pragma unroll
    for (int d = 0; d < D_; ++d) {
        float acc = bsh[d];
#pragma unroll
        for (int k = 0; k < K_; ++k) acc = fmaf(g[k], Wsh[d][k], acc);
        acc = fmaxf(acc, 0.0f);
        osh[tid][d] = acc;
        outT[(size_t)n * SLAB_ + (size_t)d * B_ + b] = acc;
    }
    __syncthreads();

    float4* region4 = (float4*)(out + (size_t)n * SLAB_ + (size_t)(bt * 256) * D_);
#pragma unroll
    for (int j = 0; j < 4; ++j) {
        int i   = j * 256 + tid;
        int row = i >> 2;
        int c0  = (i & 3) * 4;
        float4 w;
        w.x = osh[row][c0 + 0];
        w.y = osh[row][c0 + 1];
        w.z = osh[row][c0 + 2];
        w.w = osh[row][c0 + 3];
        region4[i] = w;
    }
}

extern "C" void kernel_launch(void* const* d_in, const int* in_sizes, int n_in,
                              void* d_out, int out_size, void* d_ws, size_t ws_size,
                              hipStream_t stream) {
    const float* x     = (const float*)d_in[0];
    const float* trace = (const float*)d_in[1];
    const int*   sn    = (const int*)d_in[2];
    const int*   sf    = (const int*)d_in[3];
    const float* W     = (const float*)d_in[4];
    const float* bias  = (const float*)d_in[5];
    float*       out   = (float*)d_out;

    const size_t xT_elems  = (size_t)D_ * B_;
    const size_t big_elems = (size_t)N_ * SLAB_;

    float* ws     = (float*)d_ws;
    float* xT     = ws;
    float* traceT = ws + xT_elems;
    float* outT   = traceT + big_elems;

    // Try the single fused cooperative kernel.
    void* args[] = {
        (void*)&x, (void*)&trace, (void*)&sn, (void*)&sf, (void*)&W, (void*)&bias,
        (void*)&out, (void*)&xT, (void*)&traceT, (void*)&outT
    };
    hipError_t err = hipLaunchCooperativeKernel((const void*)fused_all,
                                                dim3(NBLK), dim3(256),
                                                args, 0, stream);
    if (err == hipSuccess) return;

    // Fallback: multi-dispatch path (kernel-boundary ordering + cache flushes).
    transpose_bd<<<N_ * 32 + 32, 256, 0, stream>>>(trace, x, traceT, xT);
    for (int l = 0; l < L_; ++l) {
        layer_kernel<<<M_ * 8, 256, 0, stream>>>(
            l, xT, traceT, outT, sn, sf, W, bias, out, outT);
    }
}

// Round 4
// 1262.658 us; speedup vs baseline: 1.6443x; 1.6443x over previous
//
#include <hip/hip_runtime.h>

#define L_ 8
#define M_ 128
#define K_ 32
#define D_ 16
#define B_ 2048
#define N_ 1024           // L_*M_
#define SLAB_ 32768       // B_*D_ elements per node slab
#define NFLAGS (N_ * 8)   // one flag per (node, b-tile-of-256)

// ===========================================================================
// Dispatch 1: transpose (B_,D_) slabs -> (D_,B_) + zero the flag array.
// grid = N_*8 + 8 = 8200 blocks, 256 threads; one 256b x 16d tile per block.
// ===========================================================================
__global__ __launch_bounds__(256) void transpose_bd(const float* __restrict__ trace,
                                                    const float* __restrict__ x,
                                                    float* __restrict__ traceT,
                                                    float* __restrict__ xT,
                                                    int* __restrict__ flags)
{
    const int t   = blockIdx.x;
    const int tid = threadIdx.x;
    if (t < 32) flags[t * 256 + tid] = 0;   // 32*256 = 8192 flags zeroed

    const float* src; float* dst; int bt;
    if (t < N_ * 8) {
        const int nn = t >> 3;
        src = trace + (size_t)nn * SLAB_;
        dst = traceT + (size_t)nn * SLAB_;
        bt  = t & 7;
    } else {
        src = x; dst = xT; bt = t - N_ * 8;
    }
    const int b0 = bt * 256;

    __shared__ float lds[16 * 257];   // row stride 257: both phases <=2-way banks

    // Load: thread tid owns b-row (b0+tid): 16 floats = 4 float4, 16 KB/block contiguous.
    const float4* s4 = (const float4*)(src + (size_t)b0 * D_);
    float4 v0 = s4[tid * 4 + 0];
    float4 v1 = s4[tid * 4 + 1];
    float4 v2 = s4[tid * 4 + 2];
    float4 v3 = s4[tid * 4 + 3];
    lds[ 0 * 257 + tid] = v0.x;  lds[ 1 * 257 + tid] = v0.y;
    lds[ 2 * 257 + tid] = v0.z;  lds[ 3 * 257 + tid] = v0.w;
    lds[ 4 * 257 + tid] = v1.x;  lds[ 5 * 257 + tid] = v1.y;
    lds[ 6 * 257 + tid] = v1.z;  lds[ 7 * 257 + tid] = v1.w;
    lds[ 8 * 257 + tid] = v2.x;  lds[ 9 * 257 + tid] = v2.y;
    lds[10 * 257 + tid] = v2.z;  lds[11 * 257 + tid] = v2.w;
    lds[12 * 257 + tid] = v3.x;  lds[13 * 257 + tid] = v3.y;
    lds[14 * 257 + tid] = v3.z;  lds[15 * 257 + tid] = v3.w;
    __syncthreads();

    // Store: 16 d-rows x 256 b, 4 float4/thread, 1 KB-contiguous row chunks.
    const int d  = tid >> 4;
    const int q0 = tid & 15;
    float* drow = dst + (size_t)d * B_ + b0;
#pragma unroll
    for (int j = 0; j < 4; ++j) {
        const int bq = q0 + 16 * j;
        float4 w;
        w.x = lds[d * 257 + 4 * bq + 0];
        w.y = lds[d * 257 + 4 * bq + 1];
        w.z = lds[d * 257 + 4 * bq + 2];
        w.w = lds[d * 257 + 4 * bq + 3];
        ((float4*)drow)[bq] = w;
    }
}

// ===========================================================================
// Dispatch 2: all 8 layers in one persistent kernel with fine-grained flag
// sync. grid = 1024 blocks (m, bt), 256 threads (one b each).
// Residency: ~20 KB LDS + launch_bounds(256,4) -> 4 blocks/CU x 256 CU = 1024,
// so every block is co-resident and spin-waiting is deadlock-free.
// Dependency structure: consumer (m,bt,l) only ever reads b-range of the SAME
// bt from producers at layers < l -> wait on flag[(s-1)*8 + bt].
// ===========================================================================
__global__ __launch_bounds__(256, 4) void layers_flag(
    const float* __restrict__ xT, const float* __restrict__ traceT,
    float* __restrict__ outT,
    const int* __restrict__ sn, const int* __restrict__ sf,
    const float* __restrict__ W, const float* __restrict__ bias,
    float* __restrict__ out, int* __restrict__ flags)
{
    const int tid = threadIdx.x;
    const int m   = blockIdx.x >> 3;
    const int bt  = blockIdx.x & 7;
    const int b   = bt * 256 + tid;

    __shared__ float        Wsh[D_ * K_];
    __shared__ float        bsh[D_];
    __shared__ const float* colp[K_];
    __shared__ int          waitn[K_];
    __shared__ float        osh[256 * 17];

    for (int l = 0; l < L_; ++l) {
        const int n = l * M_ + m;

        if (tid < 128) {
            ((float4*)Wsh)[tid] = ((const float4*)(W + (size_t)n * D_ * K_))[tid];
        }
        if (tid < D_) bsh[tid] = bias[(size_t)n * D_ + tid];
        if (tid < K_) {
            const int s = sn[(size_t)n * K_ + tid];
            const int f = sf[(size_t)n * K_ + tid];
            const float* p;
            int wn = -1;
            if (s == 0) {
                p = xT + (size_t)f * B_;
            } else {
                const int ls = (s - 1) >> 7;
                if (ls >= l) {
                    p = traceT + (size_t)(s - 1) * SLAB_ + (size_t)f * B_;
                } else {
                    p  = outT + (size_t)(s - 1) * SLAB_ + (size_t)f * B_;
                    wn = s - 1;                    // must wait for this node
                }
            }
            colp[tid]  = p;
            waitn[tid] = wn;
        }
        __syncthreads();

        // Spin on the <=32 producer flags (same bt). Layer 0 never waits.
        if (tid < K_) {
            const int wn = waitn[tid];
            if (wn >= 0) {
                while (__hip_atomic_load(&flags[wn * 8 + bt], __ATOMIC_RELAXED,
                                         __HIP_MEMORY_SCOPE_AGENT) == 0) {
                    __builtin_amdgcn_s_sleep(8);
                }
            }
        }
        __syncthreads();
        __builtin_amdgcn_fence(__ATOMIC_ACQUIRE, "agent");   // outT reads see producer data

        // Gather: 32 coalesced 256 B wave-loads.
        float g[K_];
#pragma unroll
        for (int k = 0; k < K_; ++k) g[k] = colp[k][b];

        // o[d] = relu(bias + g . W[d,:]); stage osh; write outT (layer 7 is
        // never a gather source -> skip its outT write + flag).
        const bool produce = (l < L_ - 1);
#pragma unroll
        for (int d = 0; d < D_; ++d) {
            float acc = bsh[d];
#pragma unroll
            for (int k = 0; k < K_; ++k) acc = fmaf(g[k], Wsh[d * K_ + k], acc);
            acc = fmaxf(acc, 0.0f);
            osh[tid * 17 + d] = acc;
            if (produce) outT[(size_t)n * SLAB_ + (size_t)d * B_ + b] = acc;
        }

        if (produce) {
            __builtin_amdgcn_fence(__ATOMIC_RELEASE, "agent"); // push outT to coherence point
            __syncthreads();                                    // all waves' fences done
            if (tid == 0) {
                __hip_atomic_store(&flags[n * 8 + bt], 1, __ATOMIC_RELAXED,
                                   __HIP_MEMORY_SCOPE_AGENT);
            }
        } else {
            __syncthreads();
        }

        // Native out: block region out[n, bt*256.., :] = 16 KB contiguous.
        float4* region4 = (float4*)(out + (size_t)n * SLAB_ + (size_t)(bt * 256) * D_);
#pragma unroll
        for (int j = 0; j < 4; ++j) {
            const int i   = j * 256 + tid;
            const int row = i >> 2;
            const int c0  = (i & 3) * 4;
            float4 w;
            w.x = osh[row * 17 + c0 + 0];
            w.y = osh[row * 17 + c0 + 1];
            w.z = osh[row * 17 + c0 + 2];
            w.w = osh[row * 17 + c0 + 3];
            region4[i] = w;
        }
        // osh/colp/Wsh reuse is safe: next layer writes them only after its
        // first __syncthreads, which follows everyone's region stores.
    }
}

extern "C" void kernel_launch(void* const* d_in, const int* in_sizes, int n_in,
                              void* d_out, int out_size, void* d_ws, size_t ws_size,
                              hipStream_t stream) {
    const float* x     = (const float*)d_in[0];
    const float* trace = (const float*)d_in[1];
    const int*   sn    = (const int*)d_in[2];
    const int*   sf    = (const int*)d_in[3];
    const float* W     = (const float*)d_in[4];
    const float* bias  = (const float*)d_in[5];
    float*       out   = (float*)d_out;

    const size_t xT_elems  = (size_t)D_ * B_;        // 32768
    const size_t big_elems = (size_t)N_ * SLAB_;     // 33554432

    float* ws     = (float*)d_ws;
    float* xT     = ws;
    float* traceT = ws + xT_elems;
    float* outT   = traceT + big_elems;
    int*   flags  = (int*)(outT + big_elems);        // 8192 ints; ws is 512 MB >> need

    transpose_bd<<<N_ * 8 + 8, 256, 0, stream>>>(trace, x, traceT, xT, flags);
    layers_flag<<<N_, 256, 0, stream>>>(xT, traceT, outT, sn, sf, W, bias, out, flags);
}